// Round 9
// baseline (417.446 us; speedup 1.0000x reference)
//
#include <hip/hip_runtime.h>
#include <hip/hip_bf16.h>

typedef unsigned short ushort_t;
typedef __attribute__((ext_vector_type(8))) short short8;
typedef __attribute__((ext_vector_type(4))) float f32x4;

// ---------------- problem constants ----------------
// conv1: x[128,1,28,28]*w[256,1,9,9] s1 -> h1t[128,20,20,256] (NHWC bf16)
// caps1: implicit GEMM M=4608(b,pos) N=256(co) K=81*256, split-K by ci-quarter
//        1-wave blocks, direct global->register fragments, no LDS/barriers
// u_hat: materialized bf16 [b][q][p][16]; routing p=1152, q=10; output f32.

// ---------------- ws layout (bytes) ----------------
#define OFFB_H1T  0u           // 26,214,400
#define OFFB_WT   26214400u    // 10,616,832
#define OFFB_PART 36831232u    // 18,874,368
#define OFFB_H2   55705600u    //  4,718,592
#define OFFB_UH   60424192u    // 47,185,920
#define OFFB_BIJ  107610112u   //  5,898,240
#define OFFB_C    113508352u   //  5,898,240
#define OFFB_V    119406592u   //     81,920
#define OFFB_F1   119488512u   //    262,144
#define OFFB_F2   119750656u   //    524,288
#define OFFB_W1T  120274944u   //     82,944  -> total ~120.4 MB

__device__ __forceinline__ ushort_t f2bf(float f) {
  union { float f; unsigned int u; } c; c.f = f;
  unsigned int r = (c.u + 0x7FFFu + ((c.u >> 16) & 1u)) >> 16;
  return (ushort_t)r;
}
__device__ __forceinline__ float bf2f(ushort_t u) {
  union { unsigned int i; float f; } c; c.i = ((unsigned int)u) << 16;
  return c.f;
}

// ========== conv1 weight transpose: w[co][kk] -> w1t[kk][co] f32 ==========
__global__ __launch_bounds__(256) void w1t_kernel(
    const float* __restrict__ w, float* __restrict__ w1t) {
  int kk = blockIdx.x;    // 81
  int co = threadIdx.x;   // 256
  w1t[kk * 256 + co] = w[co * 81 + kk];
}

// ================= conv1 + relu -> NHWC bf16 =================
// grid = b*20+oy (2560), block 256 (t = co); weight loads now coalesced.
__global__ __launch_bounds__(256) void conv1_kernel(
    const float* __restrict__ x, const float* __restrict__ w1t,
    const float* __restrict__ bias, ushort_t* __restrict__ h1t) {
  int blk = blockIdx.x;
  int b = blk / 20, oy = blk % 20;
  int co = threadIdx.x;
  __shared__ float xs[252];
  for (int l = co; l < 252; l += 256)
    xs[l] = x[b * 784 + (oy + l / 28) * 28 + (l % 28)];
  __syncthreads();
  float bs = bias[co];
  float acc[20];
#pragma unroll
  for (int i = 0; i < 20; ++i) acc[i] = bs;
  for (int ky = 0; ky < 9; ++ky) {
    float xr[28];
#pragma unroll
    for (int i = 0; i < 28; ++i) xr[i] = xs[ky * 28 + i];
    float wk[9];
#pragma unroll
    for (int kx = 0; kx < 9; ++kx) wk[kx] = w1t[(ky * 9 + kx) * 256 + co];
#pragma unroll
    for (int kx = 0; kx < 9; ++kx)
#pragma unroll
      for (int ox = 0; ox < 20; ++ox) acc[ox] += wk[kx] * xr[ox + kx];
  }
  int xb = (b * 20 + oy) * 20;
#pragma unroll
  for (int ox = 0; ox < 20; ++ox)
    h1t[(xb + ox) * 256 + co] = f2bf(fmaxf(acc[ox], 0.f));
}

// ========== caps1 weight reorder: w[co][ci][kk] -> wt[kk][co][ci] bf16 =====
__global__ __launch_bounds__(256) void wreorder_kernel(
    const float* __restrict__ w, ushort_t* __restrict__ wt) {
  int co = blockIdx.x;
  __shared__ ushort_t wl[256 * 82];
  int t = threadIdx.x;
  const float* src = w + (size_t)co * 20736;
  for (int e = t; e < 20736; e += 256) {
    int ci = e / 81, kk = e - ci * 81;
    wl[ci * 82 + kk] = f2bf(src[e]);
  }
  __syncthreads();
  for (int kk = 0; kk < 81; ++kk)
    wt[((size_t)kk * 256 + co) * 256 + t] = wl[t * 82 + kk];
}

// ============ caps1 implicit GEMM: 1-wave blocks, LDS-free ============
// 1152 blocks x 64 threads. Wave computes 64x64 output. Fragments loaded
// directly global->VGPR (16-row groups form contiguous 64B lines).
// Register ping-pong double buffer; no barriers at all.
__global__ __launch_bounds__(64) void caps1_gemm(
    const ushort_t* __restrict__ h1t, const ushort_t* __restrict__ wt,
    float* __restrict__ part) {
  int lb = (blockIdx.x & 7) * 144 + (blockIdx.x >> 3);  // XCD-bijective
  int chunk = lb / 288;            // ci quarter
  int tile = lb - chunk * 288;
  int gm0 = (tile >> 2) * 64;
  int gn0 = (tile & 3) * 64;
  int ci0 = chunk << 6;
  int lane = threadIdx.x;
  int lr = lane & 15, lg = lane >> 4;

  const ushort_t* ab[4];
#pragma unroll
  for (int mf = 0; mf < 4; ++mf) {
    int m = gm0 + mf * 16 + lr;
    int b = m / 36, pos = m - b * 36;
    int oy = pos / 6, ox = pos - oy * 6;
    ab[mf] = h1t + ((b * 20 + 2 * oy) * 20 + 2 * ox) * 256 + ci0 + lg * 8;
  }
  const ushort_t* bb[4];
#pragma unroll
  for (int nf = 0; nf < 4; ++nf)
    bb[nf] = wt + (size_t)(gn0 + nf * 16 + lr) * 256 + ci0 + lg * 8;

  f32x4 acc[4][4];
#pragma unroll
  for (int i = 0; i < 4; ++i)
#pragma unroll
    for (int j = 0; j < 4; ++j)
#pragma unroll
      for (int e = 0; e < 4; ++e) acc[i][j][e] = 0.f;

  short8 aA[4][2], bA[4][2], aB[4][2], bB[4][2];

#define LDA(dst, kkv)                                                    \
  {                                                                      \
    int ky_ = (kkv) / 9, kx_ = (kkv) - ky_ * 9;                          \
    int off_ = (ky_ * 20 + kx_) * 256;                                   \
    _Pragma("unroll") for (int mf_ = 0; mf_ < 4; ++mf_)                  \
        _Pragma("unroll") for (int kh_ = 0; kh_ < 2; ++kh_)              \
            dst[mf_][kh_] = *(const short8*)(ab[mf_] + off_ + kh_ * 32); \
  }
#define LDB(dst, kkv)                                                    \
  {                                                                      \
    size_t off_ = (size_t)(kkv)*65536;                                   \
    _Pragma("unroll") for (int nf_ = 0; nf_ < 4; ++nf_)                  \
        _Pragma("unroll") for (int kh_ = 0; kh_ < 2; ++kh_)              \
            dst[nf_][kh_] = *(const short8*)(bb[nf_] + off_ + kh_ * 32); \
  }
#define MM(af, bf)                                                       \
  _Pragma("unroll") for (int kh_ = 0; kh_ < 2; ++kh_)                    \
      _Pragma("unroll") for (int mf_ = 0; mf_ < 4; ++mf_)                \
          _Pragma("unroll") for (int nf_ = 0; nf_ < 4; ++nf_)            \
              acc[mf_][nf_] = __builtin_amdgcn_mfma_f32_16x16x32_bf16(   \
                  af[mf_][kh_], bf[nf_][kh_], acc[mf_][nf_], 0, 0, 0);

  LDA(aA, 0);
  LDB(bA, 0);
  for (int kk = 0; kk < 80; kk += 2) {
    LDA(aB, kk + 1);
    LDB(bB, kk + 1);
    MM(aA, bA);
    LDA(aA, kk + 2);   // kk+2 <= 80
    LDB(bA, kk + 2);
    MM(aB, bB);
  }
  MM(aA, bA);  // kk = 80

  float* pbase = part + (size_t)chunk * 4608 * 256;
#pragma unroll
  for (int mf = 0; mf < 4; ++mf)
#pragma unroll
    for (int nf = 0; nf < 4; ++nf) {
      int nn = gn0 + nf * 16 + lr;
#pragma unroll
      for (int reg = 0; reg < 4; ++reg) {
        int mm = gm0 + mf * 16 + lg * 4 + reg;
        pbase[(size_t)mm * 256 + nn] = acc[mf][nf][reg];
      }
    }
#undef LDA
#undef LDB
#undef MM
}

// ========= reduce: h2[m][n] = relu(sum_c part[c][m][n] + bias[n]) =========
__global__ __launch_bounds__(256) void reduce_kernel(
    const float* __restrict__ part, const float* __restrict__ bias,
    float* __restrict__ h2) {
  int m = blockIdx.x;
  int n = threadIdx.x;
  size_t o = (size_t)m * 256 + n;
  float s = part[o] + part[o + 4608 * 256] + part[o + 2 * 4608 * 256] +
            part[o + 3 * 4608 * 256];
  h2[o] = fmaxf(s + bias[n], 0.f);
}

// ================= u_hat materialize (W-local, LDS-staged) ============
__global__ __launch_bounds__(256) void uhat_kernel(
    const float* __restrict__ h2, const float* __restrict__ W,
    ushort_t* __restrict__ uh) {
  int blk = blockIdx.x;
  int bh = blk & 1;
  int qpc = blk >> 1;
  int q = qpc / 72;
  int pc = qpc - q * 72;
  int p0 = pc * 16;
  int b0 = bh * 64;
  __shared__ float Wl[16][132];
  __shared__ float xl[64][16][9];
  int t = threadIdx.x;
#pragma unroll
  for (int it = 0; it < 2; ++it) {
    int idx = t * 2 + it;
    int row = idx >> 5;
    int c4 = idx & 31;
    float4 vv = *(reinterpret_cast<const float4*>(
        &W[(size_t)((p0 + row) * 10 + q) * 128]) + c4);
    Wl[row][c4 * 4 + 0] = vv.x;
    Wl[row][c4 * 4 + 1] = vv.y;
    Wl[row][c4 * 4 + 2] = vv.z;
    Wl[row][c4 * 4 + 3] = vv.w;
  }
  for (int j = 0; j < 32; ++j) {
    int e = t + 256 * j;
    int b_l = e >> 7;
    int rem = e & 127;
    int i = rem >> 3, n = rem & 7;
    int f = (p0 + i) * 80 + q * 8 + n;
    xl[b_l][i][n] = h2[((size_t)(b0 + b_l) * 36 + (f % 36)) * 256 + (f / 360)];
  }
  __syncthreads();
  int p_l = t & 15;
  int b_ll = t >> 4;
  const float* wr = &Wl[p_l][0];
#pragma unroll
  for (int k = 0; k < 4; ++k) {
    int b_l = b_ll + 16 * k;
    float xv[8];
#pragma unroll
    for (int n = 0; n < 8; ++n) xv[n] = xl[b_l][p_l][n];
    short8 o0, o1;
#pragma unroll
    for (int a = 0; a < 8; ++a) {
      float ue = 0.f, uo = 0.f;
#pragma unroll
      for (int n = 0; n < 8; ++n) {
        ue += wr[a * 16 + n] * xv[n];
        uo += wr[a * 16 + 8 + n] * xv[n];
      }
      if (a < 4) { o0[2 * a] = (short)f2bf(ue); o0[2 * a + 1] = (short)f2bf(uo); }
      else { o1[2 * (a - 4)] = (short)f2bf(ue); o1[2 * (a - 4) + 1] = (short)f2bf(uo); }
    }
    size_t dst = ((size_t)((b0 + b_l) * 10 + q) * 1152 + p0 + p_l) * 16;
    *(short8*)&uh[dst] = o0;
    *(short8*)&uh[dst + 8] = o1;
  }
}

// ================= sv: weighted sum + squash =================
template <int MODE>
__global__ __launch_bounds__(64) void sv_kernel(
    const ushort_t* __restrict__ uh, const float* __restrict__ cbuf,
    const float* __restrict__ caps_bias, float* __restrict__ v,
    float* __restrict__ out) {
  int bq = blockIdx.x;
  int q = bq % 10;
  int t = threadIdx.x;
  const ushort_t* ub = &uh[(size_t)bq * 1152 * 16];
  const float* cb = &cbuf[(size_t)bq * 1152];
  float s[16];
#pragma unroll
  for (int m = 0; m < 16; ++m) s[m] = 0.f;
  for (int p = t; p < 1152; p += 64) {
    short8 u0 = *(const short8*)&ub[p * 16];
    short8 u1 = *(const short8*)&ub[p * 16 + 8];
    float c = (MODE == 0) ? 0.1f : cb[p];
#pragma unroll
    for (int m = 0; m < 8; ++m) s[m] += c * bf2f((ushort_t)u0[m]);
#pragma unroll
    for (int m = 0; m < 8; ++m) s[8 + m] += c * bf2f((ushort_t)u1[m]);
  }
#pragma unroll
  for (int m = 0; m < 16; ++m) {
    float val = s[m];
#pragma unroll
    for (int off = 32; off > 0; off >>= 1) val += __shfl_down(val, off);
    s[m] = val;
  }
  if (t == 0) {
    float sq = 0.f;
#pragma unroll
    for (int m = 0; m < 16; ++m) {
      s[m] += caps_bias[q * 16 + m];
      sq += s[m] * s[m];
    }
    float coef = (sq / (1.f + sq)) * rsqrtf(sq + 1e-9f);
    float vl2 = 0.f;
#pragma unroll
    for (int m = 0; m < 16; ++m) {
      float vv = coef * s[m];
      v[bq * 16 + m] = vv;
      vl2 += vv * vv;
    }
    if (MODE == 2) out[bq] = sqrtf(vl2 + 1e-9f);
  }
}

// ======== agree: d=u.v, bij update, fused softmax -> c ========
template <bool FIRST>
__global__ __launch_bounds__(256) void agree_kernel(
    const ushort_t* __restrict__ uh, const float* __restrict__ v,
    float* __restrict__ bij, float* __restrict__ cbuf) {
  int tid = blockIdx.x * 256 + threadIdx.x;
  int b = tid / 1152;
  int p = tid - b * 1152;
  float br[10];
  float* bp = &bij[(size_t)tid * 10];
#pragma unroll
  for (int q = 0; q < 10; ++q) {
    const ushort_t* ub = &uh[(size_t)((b * 10 + q) * 1152 + p) * 16];
    short8 u0 = *(const short8*)ub;
    short8 u1 = *(const short8*)(ub + 8);
    const float4* v4 = reinterpret_cast<const float4*>(&v[(b * 10 + q) * 16]);
    float4 b0 = v4[0], b1 = v4[1], b2 = v4[2], b3 = v4[3];
    float d = bf2f((ushort_t)u0[0]) * b0.x + bf2f((ushort_t)u0[1]) * b0.y
            + bf2f((ushort_t)u0[2]) * b0.z + bf2f((ushort_t)u0[3]) * b0.w
            + bf2f((ushort_t)u0[4]) * b1.x + bf2f((ushort_t)u0[5]) * b1.y
            + bf2f((ushort_t)u0[6]) * b1.z + bf2f((ushort_t)u0[7]) * b1.w
            + bf2f((ushort_t)u1[0]) * b2.x + bf2f((ushort_t)u1[1]) * b2.y
            + bf2f((ushort_t)u1[2]) * b2.z + bf2f((ushort_t)u1[3]) * b2.w
            + bf2f((ushort_t)u1[4]) * b3.x + bf2f((ushort_t)u1[5]) * b3.y
            + bf2f((ushort_t)u1[6]) * b3.z + bf2f((ushort_t)u1[7]) * b3.w;
    br[q] = (FIRST ? 0.f : bp[q]) + d;
  }
  float mx = br[0];
#pragma unroll
  for (int q = 1; q < 10; ++q) mx = fmaxf(mx, br[q]);
  float den = 0.f;
  float ex[10];
#pragma unroll
  for (int q = 0; q < 10; ++q) { ex[q] = __expf(br[q] - mx); den += ex[q]; }
  float inv = 1.f / den;
#pragma unroll
  for (int q = 0; q < 10; ++q) {
    bp[q] = br[q];
    cbuf[(size_t)(b * 10 + q) * 1152 + p] = ex[q] * inv;
  }
}

// ================= fc1: masked_v + fc1 =================
__global__ __launch_bounds__(128) void fc1_kernel(
    const float* __restrict__ v, const float* __restrict__ y,
    const float* __restrict__ fc1_w, const float* __restrict__ fc1_b,
    float* __restrict__ f1g) {
  int b = blockIdx.x, t = threadIdx.x;
  __shared__ float mv[16];
  if (t < 16) {
    const float* vb = &v[b * 160];
    float a = 0.f;
#pragma unroll
    for (int tt = 0; tt < 10; ++tt) a += vb[t * 10 + tt] * y[b * 10 + tt];
    mv[t] = a;
  }
  __syncthreads();
  for (int o = t; o < 512; o += 128) {
    const float4* wr = reinterpret_cast<const float4*>(&fc1_w[o * 16]);
    float4 w0 = wr[0], w1 = wr[1], w2 = wr[2], w3 = wr[3];
    f1g[b * 512 + o] = fc1_b[o]
        + mv[0] * w0.x + mv[1] * w0.y + mv[2] * w0.z + mv[3] * w0.w
        + mv[4] * w1.x + mv[5] * w1.y + mv[6] * w1.z + mv[7] * w1.w
        + mv[8] * w2.x + mv[9] * w2.y + mv[10] * w2.z + mv[11] * w2.w
        + mv[12] * w3.x + mv[13] * w3.y + mv[14] * w3.z + mv[15] * w3.w;
  }
}

// ================= fc2 =================
__global__ __launch_bounds__(256) void fc2_kernel(
    const float* __restrict__ f1g, const float* __restrict__ fc2_w,
    const float* __restrict__ fc2_b, float* __restrict__ f2g) {
  int b = blockIdx.x >> 2;
  int o = (blockIdx.x & 3) * 256 + threadIdx.x;
  __shared__ float f1[512];
  for (int l = threadIdx.x; l < 512; l += 256) f1[l] = f1g[b * 512 + l];
  __syncthreads();
  const float4* wr = reinterpret_cast<const float4*>(&fc2_w[o * 512]);
  float a = fc2_b[o];
#pragma unroll 4
  for (int k4 = 0; k4 < 128; ++k4) {
    float4 w4 = wr[k4];
    a += f1[4 * k4] * w4.x + f1[4 * k4 + 1] * w4.y + f1[4 * k4 + 2] * w4.z +
         f1[4 * k4 + 3] * w4.w;
  }
  f2g[b * 1024 + o] = a;
}

// ================= fc3 + sigmoid =================
__global__ __launch_bounds__(256) void fc3_kernel(
    const float* __restrict__ f2g, const float* __restrict__ fc3_w,
    const float* __restrict__ fc3_b, float* __restrict__ out) {
  int b = blockIdx.x >> 2;
  int oc = (blockIdx.x & 3) * 196;
  __shared__ float f2[1024];
  for (int l = threadIdx.x; l < 1024; l += 256) f2[l] = f2g[b * 1024 + l];
  __syncthreads();
  if (threadIdx.x >= 196) return;
  int o = oc + threadIdx.x;
  const float4* wr = reinterpret_cast<const float4*>(&fc3_w[o * 1024]);
  float a = fc3_b[o];
#pragma unroll 4
  for (int k4 = 0; k4 < 256; ++k4) {
    float4 w4 = wr[k4];
    a += f2[4 * k4] * w4.x + f2[4 * k4 + 1] * w4.y + f2[4 * k4 + 2] * w4.z +
         f2[4 * k4 + 3] * w4.w;
  }
  out[1280 + b * 784 + o] = 1.f / (1.f + __expf(-a));
}

extern "C" void kernel_launch(void* const* d_in, const int* in_sizes, int n_in,
                              void* d_out, int out_size, void* d_ws, size_t ws_size,
                              hipStream_t stream) {
  const float* x       = (const float*)d_in[0];
  const float* y       = (const float*)d_in[1];
  const float* conv1_w = (const float*)d_in[2];
  const float* conv1_b = (const float*)d_in[3];
  const float* caps1_w = (const float*)d_in[4];
  const float* caps1_b = (const float*)d_in[5];
  const float* W       = (const float*)d_in[6];
  const float* cbias   = (const float*)d_in[7];
  const float* fc1_w   = (const float*)d_in[8];
  const float* fc1_b   = (const float*)d_in[9];
  const float* fc2_w   = (const float*)d_in[10];
  const float* fc2_b   = (const float*)d_in[11];
  const float* fc3_w   = (const float*)d_in[12];
  const float* fc3_b   = (const float*)d_in[13];
  float* out = (float*)d_out;

  char* wsb = (char*)d_ws;
  ushort_t* h1t  = (ushort_t*)(wsb + OFFB_H1T);
  ushort_t* wt   = (ushort_t*)(wsb + OFFB_WT);
  float*    part = (float*)(wsb + OFFB_PART);
  float*    h2   = (float*)(wsb + OFFB_H2);
  ushort_t* uh   = (ushort_t*)(wsb + OFFB_UH);
  float*    bij  = (float*)(wsb + OFFB_BIJ);
  float*    c    = (float*)(wsb + OFFB_C);
  float*    v    = (float*)(wsb + OFFB_V);
  float*    f1   = (float*)(wsb + OFFB_F1);
  float*    f2   = (float*)(wsb + OFFB_F2);
  float*    w1t  = (float*)(wsb + OFFB_W1T);

  w1t_kernel<<<81, 256, 0, stream>>>(conv1_w, w1t);
  conv1_kernel<<<2560, 256, 0, stream>>>(x, w1t, conv1_b, h1t);
  wreorder_kernel<<<256, 256, 0, stream>>>(caps1_w, wt);
  caps1_gemm<<<1152, 64, 0, stream>>>(h1t, wt, part);
  reduce_kernel<<<4608, 256, 0, stream>>>(part, caps1_b, h2);
  uhat_kernel<<<1440, 256, 0, stream>>>(h2, W, uh);

  sv_kernel<0><<<1280, 64, 0, stream>>>(uh, c, cbias, v, out);
  agree_kernel<true><<<576, 256, 0, stream>>>(uh, v, bij, c);
  sv_kernel<1><<<1280, 64, 0, stream>>>(uh, c, cbias, v, out);
  agree_kernel<false><<<576, 256, 0, stream>>>(uh, v, bij, c);
  sv_kernel<2><<<1280, 64, 0, stream>>>(uh, c, cbias, v, out);

  fc1_kernel<<<128, 128, 0, stream>>>(v, y, fc1_w, fc1_b, f1);
  fc2_kernel<<<512, 256, 0, stream>>>(f1, fc2_w, fc2_b, f2);
  fc3_kernel<<<512, 256, 0, stream>>>(f2, fc3_w, fc3_b, out);
}

// Round 10
// 330.551 us; speedup vs baseline: 1.2629x; 1.2629x over previous
//
#include <hip/hip_runtime.h>
#include <hip/hip_bf16.h>

typedef unsigned short ushort_t;
typedef __attribute__((ext_vector_type(8))) short short8;
typedef __attribute__((ext_vector_type(4))) float f32x4;

// ---------------- problem constants ----------------
// conv1: x[128,1,28,28]*w[256,1,9,9] s1 -> h1t[128,20,20,256] (NHWC bf16)
// caps1: implicit GEMM M=4608(b,pos) N=256(co) K=81*256, split-K by ci-quarter
//        128x64 tile, 8 waves, LDS dbuf + XOR swizzle (r8 structure, retiled)
// u_hat: materialized bf16 [b][q][p][16]; routing p=1152, q=10; output f32.

// ---------------- ws layout (bytes) ----------------
#define OFFB_H1T  0u           // 26,214,400
#define OFFB_WT   26214400u    // 10,616,832
#define OFFB_PART 36831232u    // 18,874,368
#define OFFB_H2   55705600u    //  4,718,592
#define OFFB_UH   60424192u    // 47,185,920
#define OFFB_BIJ  107610112u   //  5,898,240
#define OFFB_C    113508352u   //  5,898,240
#define OFFB_V    119406592u   //     81,920
#define OFFB_F1   119488512u   //    262,144
#define OFFB_F2   119750656u   //    524,288
#define OFFB_W1T  120274944u   //     82,944  -> total ~120.4 MB

__device__ __forceinline__ ushort_t f2bf(float f) {
  union { float f; unsigned int u; } c; c.f = f;
  unsigned int r = (c.u + 0x7FFFu + ((c.u >> 16) & 1u)) >> 16;
  return (ushort_t)r;
}
__device__ __forceinline__ float bf2f(ushort_t u) {
  union { unsigned int i; float f; } c; c.i = ((unsigned int)u) << 16;
  return c.f;
}

// ========== conv1 weight transpose: w[co][kk] -> w1t[kk][co] f32 ==========
__global__ __launch_bounds__(256) void w1t_kernel(
    const float* __restrict__ w, float* __restrict__ w1t) {
  int kk = blockIdx.x;
  int co = threadIdx.x;
  w1t[kk * 256 + co] = w[co * 81 + kk];
}

// ================= conv1 + relu -> NHWC bf16 =================
__global__ __launch_bounds__(256) void conv1_kernel(
    const float* __restrict__ x, const float* __restrict__ w1t,
    const float* __restrict__ bias, ushort_t* __restrict__ h1t) {
  int blk = blockIdx.x;
  int b = blk / 20, oy = blk % 20;
  int co = threadIdx.x;
  __shared__ float xs[252];
  for (int l = co; l < 252; l += 256)
    xs[l] = x[b * 784 + (oy + l / 28) * 28 + (l % 28)];
  __syncthreads();
  float bs = bias[co];
  float acc[20];
#pragma unroll
  for (int i = 0; i < 20; ++i) acc[i] = bs;
  for (int ky = 0; ky < 9; ++ky) {
    float xr[28];
#pragma unroll
    for (int i = 0; i < 28; ++i) xr[i] = xs[ky * 28 + i];
    float wk[9];
#pragma unroll
    for (int kx = 0; kx < 9; ++kx) wk[kx] = w1t[(ky * 9 + kx) * 256 + co];
#pragma unroll
    for (int kx = 0; kx < 9; ++kx)
#pragma unroll
      for (int ox = 0; ox < 20; ++ox) acc[ox] += wk[kx] * xr[ox + kx];
  }
  int xb = (b * 20 + oy) * 20;
#pragma unroll
  for (int ox = 0; ox < 20; ++ox)
    h1t[(xb + ox) * 256 + co] = f2bf(fmaxf(acc[ox], 0.f));
}

// ========== caps1 weight reorder: w[co][ci][kk] -> wt[kk][co][ci] bf16 =====
__global__ __launch_bounds__(256) void wreorder_kernel(
    const float* __restrict__ w, ushort_t* __restrict__ wt) {
  int co = blockIdx.x;
  __shared__ ushort_t wl[256 * 82];
  int t = threadIdx.x;
  const float* src = w + (size_t)co * 20736;
  for (int e = t; e < 20736; e += 256) {
    int ci = e / 81, kk = e - ci * 81;
    wl[ci * 82 + kk] = f2bf(src[e]);
  }
  __syncthreads();
  for (int kk = 0; kk < 81; ++kk)
    wt[((size_t)kk * 256 + co) * 256 + t] = wl[t * 82 + kk];
}

// ====== caps1 implicit GEMM: 128x64 tile, 8 waves, LDS dbuf + swizzle ======
// 576 blocks (4 chunks x 36 m x 4 n), XCD-bijective (576 = 8*72).
// 3 blocks/CU co-resident (48KB LDS), 24 waves/CU capacity.
__global__ __launch_bounds__(512) void caps1_gemm(
    const ushort_t* __restrict__ h1t, const ushort_t* __restrict__ wt,
    float* __restrict__ part) {
  int lb = (blockIdx.x & 7) * 72 + (blockIdx.x >> 3);
  int chunk = lb / 144;            // ci quarter
  int tile = lb - chunk * 144;     // 36 m x 4 n
  int gm0 = (tile >> 2) * 128;
  int gn0 = (tile & 3) * 64;
  int ci0 = chunk << 6;
  int t = threadIdx.x;
  int wave = t >> 6, lane = t & 63;
  int wm = (wave >> 1) * 32, wn = (wave & 1) * 32;  // 4 m-waves x 2 n-waves
  int lr = lane & 15, lg = lane >> 4;

  __shared__ __align__(16) ushort_t As[2][128 * 64];  // 16KB x2
  __shared__ __align__(16) ushort_t Bs[2][64 * 64];   //  8KB x2

  // A staging: row ar = t>>2 (0..127), seg = t&3 (16 ci each)
  int ar = t >> 2, aseg = t & 3;
  int am = gm0 + ar;
  int ab_ = am / 36, pos = am - ab_ * 36;
  int oy = pos / 6, ox = pos - oy * 6;
  const ushort_t* arow =
      h1t + ((ab_ * 20 + 2 * oy) * 20 + 2 * ox) * 256 + ci0 + aseg * 16;
  int ax = ar & 7;
  int ast0 = ar * 64 + (((aseg << 1) | 0) ^ ax) * 8;
  int ast1 = ar * 64 + (((aseg << 1) | 1) ^ ax) * 8;
  // B staging: row brr = t>>3 (0..63), bseg = t&7 (8 ci = one granule)
  int brr = t >> 3, bseg = t & 7;
  const ushort_t* brow = wt + (size_t)(gn0 + brr) * 256 + ci0 + bseg * 8;
  int bst = brr * 64 + (bseg ^ (brr & 7)) * 8;

  // fragment-read swizzled slots
  int lx = lr & 7;
  int sl0 = ((0 * 4 + lg) ^ lx) * 8;
  int sl1 = ((1 * 4 + lg) ^ lx) * 8;

  f32x4 acc[2][2];
#pragma unroll
  for (int i = 0; i < 2; ++i)
#pragma unroll
    for (int j = 0; j < 2; ++j)
#pragma unroll
      for (int e = 0; e < 4; ++e) acc[i][j][e] = 0.f;

  float4 ra0, ra1, rb0;
  ra0 = *(const float4*)(arow);
  ra1 = *(const float4*)(arow + 8);
  rb0 = *(const float4*)(brow);
  *(float4*)&As[0][ast0] = ra0;
  *(float4*)&As[0][ast1] = ra1;
  *(float4*)&Bs[0][bst] = rb0;
  __syncthreads();

  int buf = 0;
  for (int kk = 0; kk < 81; ++kk) {
    int nxt = kk + 1;
    if (nxt < 81) {
      int ky = nxt / 9, kx = nxt - ky * 9;
      const ushort_t* ap = arow + (ky * 20 + kx) * 256;
      ra0 = *(const float4*)(ap);
      ra1 = *(const float4*)(ap + 8);
      rb0 = *(const float4*)(brow + (size_t)nxt * 65536);
    }
    short8 af[2][2], bfr[2][2];
#pragma unroll
    for (int mf = 0; mf < 2; ++mf) {
      int ra = (wm + mf * 16 + lr) * 64;
      af[mf][0] = *(const short8*)&As[buf][ra + sl0];
      af[mf][1] = *(const short8*)&As[buf][ra + sl1];
    }
#pragma unroll
    for (int nf = 0; nf < 2; ++nf) {
      int rb = (wn + nf * 16 + lr) * 64;
      bfr[nf][0] = *(const short8*)&Bs[buf][rb + sl0];
      bfr[nf][1] = *(const short8*)&Bs[buf][rb + sl1];
    }
#pragma unroll
    for (int kh = 0; kh < 2; ++kh)
#pragma unroll
      for (int mf = 0; mf < 2; ++mf)
#pragma unroll
        for (int nf = 0; nf < 2; ++nf)
          acc[mf][nf] = __builtin_amdgcn_mfma_f32_16x16x32_bf16(
              af[mf][kh], bfr[nf][kh], acc[mf][nf], 0, 0, 0);
    __syncthreads();
    if (nxt < 81) {
      int nb = buf ^ 1;
      *(float4*)&As[nb][ast0] = ra0;
      *(float4*)&As[nb][ast1] = ra1;
      *(float4*)&Bs[nb][bst] = rb0;
      __syncthreads();
    }
    buf ^= 1;
  }

  float* pbase = part + (size_t)chunk * 4608 * 256;
#pragma unroll
  for (int mf = 0; mf < 2; ++mf)
#pragma unroll
    for (int nf = 0; nf < 2; ++nf) {
      int nn = gn0 + wn + nf * 16 + lr;
#pragma unroll
      for (int reg = 0; reg < 4; ++reg) {
        int mm = gm0 + wm + mf * 16 + lg * 4 + reg;
        pbase[(size_t)mm * 256 + nn] = acc[mf][nf][reg];
      }
    }
}

// ========= reduce: h2[m][n] = relu(sum_c part[c][m][n] + bias[n]) =========
__global__ __launch_bounds__(256) void reduce_kernel(
    const float* __restrict__ part, const float* __restrict__ bias,
    float* __restrict__ h2) {
  int m = blockIdx.x;
  int n = threadIdx.x;
  size_t o = (size_t)m * 256 + n;
  float s = part[o] + part[o + 4608 * 256] + part[o + 2 * 4608 * 256] +
            part[o + 3 * 4608 * 256];
  h2[o] = fmaxf(s + bias[n], 0.f);
}

// ================= u_hat materialize (W-local, LDS-staged) ============
__global__ __launch_bounds__(256) void uhat_kernel(
    const float* __restrict__ h2, const float* __restrict__ W,
    ushort_t* __restrict__ uh) {
  int blk = blockIdx.x;
  int bh = blk & 1;
  int qpc = blk >> 1;
  int q = qpc / 72;
  int pc = qpc - q * 72;
  int p0 = pc * 16;
  int b0 = bh * 64;
  __shared__ float Wl[16][132];
  __shared__ float xl[64][16][9];
  int t = threadIdx.x;
#pragma unroll
  for (int it = 0; it < 2; ++it) {
    int idx = t * 2 + it;
    int row = idx >> 5;
    int c4 = idx & 31;
    float4 vv = *(reinterpret_cast<const float4*>(
        &W[(size_t)((p0 + row) * 10 + q) * 128]) + c4);
    Wl[row][c4 * 4 + 0] = vv.x;
    Wl[row][c4 * 4 + 1] = vv.y;
    Wl[row][c4 * 4 + 2] = vv.z;
    Wl[row][c4 * 4 + 3] = vv.w;
  }
  for (int j = 0; j < 32; ++j) {
    int e = t + 256 * j;
    int b_l = e >> 7;
    int rem = e & 127;
    int i = rem >> 3, n = rem & 7;
    int f = (p0 + i) * 80 + q * 8 + n;
    xl[b_l][i][n] = h2[((size_t)(b0 + b_l) * 36 + (f % 36)) * 256 + (f / 360)];
  }
  __syncthreads();
  int p_l = t & 15;
  int b_ll = t >> 4;
  const float* wr = &Wl[p_l][0];
#pragma unroll
  for (int k = 0; k < 4; ++k) {
    int b_l = b_ll + 16 * k;
    float xv[8];
#pragma unroll
    for (int n = 0; n < 8; ++n) xv[n] = xl[b_l][p_l][n];
    short8 o0, o1;
#pragma unroll
    for (int a = 0; a < 8; ++a) {
      float ue = 0.f, uo = 0.f;
#pragma unroll
      for (int n = 0; n < 8; ++n) {
        ue += wr[a * 16 + n] * xv[n];
        uo += wr[a * 16 + 8 + n] * xv[n];
      }
      if (a < 4) { o0[2 * a] = (short)f2bf(ue); o0[2 * a + 1] = (short)f2bf(uo); }
      else { o1[2 * (a - 4)] = (short)f2bf(ue); o1[2 * (a - 4) + 1] = (short)f2bf(uo); }
    }
    size_t dst = ((size_t)((b0 + b_l) * 10 + q) * 1152 + p0 + p_l) * 16;
    *(short8*)&uh[dst] = o0;
    *(short8*)&uh[dst + 8] = o1;
  }
}

// ================= sv: weighted sum + squash (4 waves) =================
template <int MODE>
__global__ __launch_bounds__(256) void sv_kernel(
    const ushort_t* __restrict__ uh, const float* __restrict__ cbuf,
    const float* __restrict__ caps_bias, float* __restrict__ v,
    float* __restrict__ out) {
  int bq = blockIdx.x;
  int q = bq % 10;
  int t = threadIdx.x;
  const ushort_t* ub = &uh[(size_t)bq * 1152 * 16];
  const float* cb = &cbuf[(size_t)bq * 1152];
  float s[16];
#pragma unroll
  for (int m = 0; m < 16; ++m) s[m] = 0.f;
  for (int p = t; p < 1152; p += 256) {
    short8 u0 = *(const short8*)&ub[p * 16];
    short8 u1 = *(const short8*)&ub[p * 16 + 8];
    float c = (MODE == 0) ? 0.1f : cb[p];
#pragma unroll
    for (int m = 0; m < 8; ++m) s[m] += c * bf2f((ushort_t)u0[m]);
#pragma unroll
    for (int m = 0; m < 8; ++m) s[8 + m] += c * bf2f((ushort_t)u1[m]);
  }
  __shared__ float red[4][16];
#pragma unroll
  for (int m = 0; m < 16; ++m) {
    float val = s[m];
#pragma unroll
    for (int off = 32; off > 0; off >>= 1) val += __shfl_down(val, off);
    if ((t & 63) == 0) red[t >> 6][m] = val;
  }
  __syncthreads();
  if (t == 0) {
    float sq = 0.f;
    float sj[16];
#pragma unroll
    for (int m = 0; m < 16; ++m) {
      sj[m] = red[0][m] + red[1][m] + red[2][m] + red[3][m] +
              caps_bias[q * 16 + m];
      sq += sj[m] * sj[m];
    }
    float coef = (sq / (1.f + sq)) * rsqrtf(sq + 1e-9f);
    float vl2 = 0.f;
#pragma unroll
    for (int m = 0; m < 16; ++m) {
      float vv = coef * sj[m];
      v[bq * 16 + m] = vv;
      vl2 += vv * vv;
    }
    if (MODE == 2) out[bq] = sqrtf(vl2 + 1e-9f);
  }
}

// ======== agree: d=u.v, bij update, fused softmax -> c ========
template <bool FIRST>
__global__ __launch_bounds__(256) void agree_kernel(
    const ushort_t* __restrict__ uh, const float* __restrict__ v,
    float* __restrict__ bij, float* __restrict__ cbuf) {
  int tid = blockIdx.x * 256 + threadIdx.x;
  int b = tid / 1152;
  int p = tid - b * 1152;
  float br[10];
  float* bp = &bij[(size_t)tid * 10];
#pragma unroll
  for (int q = 0; q < 10; ++q) {
    const ushort_t* ub = &uh[(size_t)((b * 10 + q) * 1152 + p) * 16];
    short8 u0 = *(const short8*)ub;
    short8 u1 = *(const short8*)(ub + 8);
    const float4* v4 = reinterpret_cast<const float4*>(&v[(b * 10 + q) * 16]);
    float4 b0 = v4[0], b1 = v4[1], b2 = v4[2], b3 = v4[3];
    float d = bf2f((ushort_t)u0[0]) * b0.x + bf2f((ushort_t)u0[1]) * b0.y
            + bf2f((ushort_t)u0[2]) * b0.z + bf2f((ushort_t)u0[3]) * b0.w
            + bf2f((ushort_t)u0[4]) * b1.x + bf2f((ushort_t)u0[5]) * b1.y
            + bf2f((ushort_t)u0[6]) * b1.z + bf2f((ushort_t)u0[7]) * b1.w
            + bf2f((ushort_t)u1[0]) * b2.x + bf2f((ushort_t)u1[1]) * b2.y
            + bf2f((ushort_t)u1[2]) * b2.z + bf2f((ushort_t)u1[3]) * b2.w
            + bf2f((ushort_t)u1[4]) * b3.x + bf2f((ushort_t)u1[5]) * b3.y
            + bf2f((ushort_t)u1[6]) * b3.z + bf2f((ushort_t)u1[7]) * b3.w;
    br[q] = (FIRST ? 0.f : bp[q]) + d;
  }
  float mx = br[0];
#pragma unroll
  for (int q = 1; q < 10; ++q) mx = fmaxf(mx, br[q]);
  float den = 0.f;
  float ex[10];
#pragma unroll
  for (int q = 0; q < 10; ++q) { ex[q] = __expf(br[q] - mx); den += ex[q]; }
  float inv = 1.f / den;
#pragma unroll
  for (int q = 0; q < 10; ++q) {
    bp[q] = br[q];
    cbuf[(size_t)(b * 10 + q) * 1152 + p] = ex[q] * inv;
  }
}

// ================= fc1: masked_v + fc1 =================
__global__ __launch_bounds__(128) void fc1_kernel(
    const float* __restrict__ v, const float* __restrict__ y,
    const float* __restrict__ fc1_w, const float* __restrict__ fc1_b,
    float* __restrict__ f1g) {
  int b = blockIdx.x, t = threadIdx.x;
  __shared__ float mv[16];
  if (t < 16) {
    const float* vb = &v[b * 160];
    float a = 0.f;
#pragma unroll
    for (int tt = 0; tt < 10; ++tt) a += vb[t * 10 + tt] * y[b * 10 + tt];
    mv[t] = a;
  }
  __syncthreads();
  for (int o = t; o < 512; o += 128) {
    const float4* wr = reinterpret_cast<const float4*>(&fc1_w[o * 16]);
    float4 w0 = wr[0], w1 = wr[1], w2 = wr[2], w3 = wr[3];
    f1g[b * 512 + o] = fc1_b[o]
        + mv[0] * w0.x + mv[1] * w0.y + mv[2] * w0.z + mv[3] * w0.w
        + mv[4] * w1.x + mv[5] * w1.y + mv[6] * w1.z + mv[7] * w1.w
        + mv[8] * w2.x + mv[9] * w2.y + mv[10] * w2.z + mv[11] * w2.w
        + mv[12] * w3.x + mv[13] * w3.y + mv[14] * w3.z + mv[15] * w3.w;
  }
}

// ================= fc2 =================
__global__ __launch_bounds__(256) void fc2_kernel(
    const float* __restrict__ f1g, const float* __restrict__ fc2_w,
    const float* __restrict__ fc2_b, float* __restrict__ f2g) {
  int b = blockIdx.x >> 2;
  int o = (blockIdx.x & 3) * 256 + threadIdx.x;
  __shared__ float f1[512];
  for (int l = threadIdx.x; l < 512; l += 256) f1[l] = f1g[b * 512 + l];
  __syncthreads();
  const float4* wr = reinterpret_cast<const float4*>(&fc2_w[o * 512]);
  float a = fc2_b[o];
#pragma unroll 4
  for (int k4 = 0; k4 < 128; ++k4) {
    float4 w4 = wr[k4];
    a += f1[4 * k4] * w4.x + f1[4 * k4 + 1] * w4.y + f1[4 * k4 + 2] * w4.z +
         f1[4 * k4 + 3] * w4.w;
  }
  f2g[b * 1024 + o] = a;
}

// ================= fc3 + sigmoid =================
__global__ __launch_bounds__(256) void fc3_kernel(
    const float* __restrict__ f2g, const float* __restrict__ fc3_w,
    const float* __restrict__ fc3_b, float* __restrict__ out) {
  int b = blockIdx.x >> 2;
  int oc = (blockIdx.x & 3) * 196;
  __shared__ float f2[1024];
  for (int l = threadIdx.x; l < 1024; l += 256) f2[l] = f2g[b * 1024 + l];
  __syncthreads();
  if (threadIdx.x >= 196) return;
  int o = oc + threadIdx.x;
  const float4* wr = reinterpret_cast<const float4*>(&fc3_w[o * 1024]);
  float a = fc3_b[o];
#pragma unroll 4
  for (int k4 = 0; k4 < 256; ++k4) {
    float4 w4 = wr[k4];
    a += f2[4 * k4] * w4.x + f2[4 * k4 + 1] * w4.y + f2[4 * k4 + 2] * w4.z +
         f2[4 * k4 + 3] * w4.w;
  }
  out[1280 + b * 784 + o] = 1.f / (1.f + __expf(-a));
}

extern "C" void kernel_launch(void* const* d_in, const int* in_sizes, int n_in,
                              void* d_out, int out_size, void* d_ws, size_t ws_size,
                              hipStream_t stream) {
  const float* x       = (const float*)d_in[0];
  const float* y       = (const float*)d_in[1];
  const float* conv1_w = (const float*)d_in[2];
  const float* conv1_b = (const float*)d_in[3];
  const float* caps1_w = (const float*)d_in[4];
  const float* caps1_b = (const float*)d_in[5];
  const float* W       = (const float*)d_in[6];
  const float* cbias   = (const float*)d_in[7];
  const float* fc1_w   = (const float*)d_in[8];
  const float* fc1_b   = (const float*)d_in[9];
  const float* fc2_w   = (const float*)d_in[10];
  const float* fc2_b   = (const float*)d_in[11];
  const float* fc3_w   = (const float*)d_in[12];
  const float* fc3_b   = (const float*)d_in[13];
  float* out = (float*)d_out;

  char* wsb = (char*)d_ws;
  ushort_t* h1t  = (ushort_t*)(wsb + OFFB_H1T);
  ushort_t* wt   = (ushort_t*)(wsb + OFFB_WT);
  float*    part = (float*)(wsb + OFFB_PART);
  float*    h2   = (float*)(wsb + OFFB_H2);
  ushort_t* uh   = (ushort_t*)(wsb + OFFB_UH);
  float*    bij  = (float*)(wsb + OFFB_BIJ);
  float*    c    = (float*)(wsb + OFFB_C);
  float*    v    = (float*)(wsb + OFFB_V);
  float*    f1   = (float*)(wsb + OFFB_F1);
  float*    f2   = (float*)(wsb + OFFB_F2);
  float*    w1t  = (float*)(wsb + OFFB_W1T);

  w1t_kernel<<<81, 256, 0, stream>>>(conv1_w, w1t);
  conv1_kernel<<<2560, 256, 0, stream>>>(x, w1t, conv1_b, h1t);
  wreorder_kernel<<<256, 256, 0, stream>>>(caps1_w, wt);
  caps1_gemm<<<576, 512, 0, stream>>>(h1t, wt, part);
  reduce_kernel<<<4608, 256, 0, stream>>>(part, caps1_b, h2);
  uhat_kernel<<<1440, 256, 0, stream>>>(h2, W, uh);

  sv_kernel<0><<<1280, 256, 0, stream>>>(uh, c, cbias, v, out);
  agree_kernel<true><<<576, 256, 0, stream>>>(uh, v, bij, c);
  sv_kernel<1><<<1280, 256, 0, stream>>>(uh, c, cbias, v, out);
  agree_kernel<false><<<576, 256, 0, stream>>>(uh, v, bij, c);
  sv_kernel<2><<<1280, 256, 0, stream>>>(uh, c, cbias, v, out);

  fc1_kernel<<<128, 128, 0, stream>>>(v, y, fc1_w, fc1_b, f1);
  fc2_kernel<<<512, 256, 0, stream>>>(f1, fc2_w, fc2_b, f2);
  fc3_kernel<<<512, 256, 0, stream>>>(f2, fc3_w, fc3_b, out);
}